// Round 1
// baseline (531.528 us; speedup 1.0000x reference)
//
#include <hip/hip_runtime.h>

#define DEV __device__ __forceinline__

struct F3 { float x, y, z; };

DEV F3 ld3(const float* p) { F3 r; r.x = p[0]; r.y = p[1]; r.z = p[2]; return r; }
DEV F3 sub3(F3 a, F3 b) { F3 r; r.x = a.x-b.x; r.y = a.y-b.y; r.z = a.z-b.z; return r; }
DEV F3 cross3(F3 a, F3 b) {
    F3 r;
    r.x = a.y*b.z - a.z*b.y;
    r.y = a.z*b.x - a.x*b.z;
    r.z = a.x*b.y - a.y*b.x;
    return r;
}
DEV float cosv(F3 a, F3 b) {
    float num = a.x*b.x + a.y*b.y + a.z*b.z;
    float na  = a.x*a.x + a.y*a.y + a.z*a.z;
    float nb  = b.x*b.x + b.y*b.y + b.z*b.z;
    return num * rsqrtf(na * nb);
}

__global__ __launch_bounds__(256) void ori_loss_main(
    const float* __restrict__ scale,
    const int*   __restrict__ sidx,
    const int*   __restrict__ didx,
    const float* __restrict__ pred,
    const float* __restrict__ targ,
    int B, float* __restrict__ partial, int nblk)
{
    int b = blockIdx.x * 256 + threadIdx.x;
    float sumj = 0.0f, sumc = 0.0f;
    if (b < B) {
        const float s = scale[0];
        const float* pr = pred + (size_t)b * 72;
        const float* tr = targ + (size_t)b * 78;

        // smooth-L1 over 14 gathered joint pairs (indices are wave-uniform -> s_loads)
        #pragma unroll
        for (int k = 0; k < 14; ++k) {
            int sj = sidx[k] * 3;
            int dj = didx[k] * 3;
            #pragma unroll
            for (int c = 0; c < 3; ++c) {
                float d  = s * pr[sj + c] - tr[dj + c];
                float ad = fabsf(d);
                sumj += (ad < 1.0f) ? 0.5f * d * d : (ad - 0.5f);
            }
        }

        // pelvis orientation: cross(p2-p0, p1-p0) vs cross(t22-t1, t18-t1)
        {
            F3 p0 = ld3(pr + 0), p1 = ld3(pr + 3), p2 = ld3(pr + 6);
            F3 t1 = ld3(tr + 3), t18 = ld3(tr + 54), t22 = ld3(tr + 66);
            sumc += cosv(cross3(sub3(p2, p0), sub3(p1, p0)),
                         cross3(sub3(t22, t1), sub3(t18, t1)));
        }
        // chest orientation: cross(p13-p9, p14-p9) vs cross(t3-t2, t11-t2)
        {
            F3 p9 = ld3(pr + 27), p13 = ld3(pr + 39), p14 = ld3(pr + 42);
            F3 t2 = ld3(tr + 6), t3 = ld3(tr + 9), t11 = ld3(tr + 33);
            sumc += cosv(cross3(sub3(p13, p9), sub3(p14, p9)),
                         cross3(sub3(t3, t2), sub3(t11, t2)));
        }

        // 13 bone-direction cosine terms (compile-time joint indices)
        #define DIR(pa, pb, ta, tb)                                            \
            sumc += cosv(sub3(ld3(pr + (pa)*3), ld3(pr + (pb)*3)),             \
                         sub3(ld3(tr + (ta)*3), ld3(tr + (tb)*3)));
        DIR(2, 1, 22, 18)
        DIR(14, 13, 11, 4)
        DIR(6, 3, 2, 1)
        DIR(5, 2, 23, 22)
        DIR(4, 1, 19, 18)
        DIR(8, 5, 24, 23)
        DIR(7, 4, 20, 19)
        DIR(11, 8, 25, 24)
        DIR(10, 7, 21, 20)
        DIR(19, 17, 13, 12)
        DIR(18, 16, 6, 5)
        DIR(21, 19, 14, 13)
        DIR(20, 18, 7, 6)
        #undef DIR
    }

    // 64-lane wave reduction
    #pragma unroll
    for (int off = 32; off; off >>= 1) {
        sumj += __shfl_down(sumj, off);
        sumc += __shfl_down(sumc, off);
    }
    __shared__ float sj[4], sc[4];
    int wid  = threadIdx.x >> 6;
    int lane = threadIdx.x & 63;
    if (lane == 0) { sj[wid] = sumj; sc[wid] = sumc; }
    __syncthreads();
    if (threadIdx.x == 0) {
        partial[blockIdx.x]        = sj[0] + sj[1] + sj[2] + sj[3];
        partial[nblk + blockIdx.x] = sc[0] + sc[1] + sc[2] + sc[3];
    }
}

__global__ __launch_bounds__(256) void ori_loss_final(
    const float* __restrict__ partial, int nblk, int B, float* __restrict__ out)
{
    double dj = 0.0, dc = 0.0;
    for (int i = threadIdx.x; i < nblk; i += 256) {
        dj += (double)partial[i];
        dc += (double)partial[nblk + i];
    }
    #pragma unroll
    for (int off = 32; off; off >>= 1) {
        dj += __shfl_down(dj, off);
        dc += __shfl_down(dc, off);
    }
    __shared__ double wj[4], wc[4];
    int wid  = threadIdx.x >> 6;
    int lane = threadIdx.x & 63;
    if (lane == 0) { wj[wid] = dj; wc[wid] = dc; }
    __syncthreads();
    if (threadIdx.x == 0) {
        double J = wj[0] + wj[1] + wj[2] + wj[3];
        double C = wc[0] + wc[1] + wc[2] + wc[3];
        double jtr  = J / ((double)B * 42.0);
        double loss = jtr + 15.0 - C / (double)B;
        out[0] = (float)loss;
        out[1] = (float)jtr;
    }
}

extern "C" void kernel_launch(void* const* d_in, const int* in_sizes, int n_in,
                              void* d_out, int out_size, void* d_ws, size_t ws_size,
                              hipStream_t stream) {
    const float* scale = (const float*)d_in[0];
    const int*   sidx  = (const int*)d_in[1];
    const int*   didx  = (const int*)d_in[2];
    const float* pred  = (const float*)d_in[3];
    const float* targ  = (const float*)d_in[4];

    int B    = in_sizes[3] / 72;   // pred_jtr is [B, 24, 3]
    int nblk = (B + 255) / 256;

    float* partial = (float*)d_ws;
    float* out     = (float*)d_out;

    ori_loss_main<<<nblk, 256, 0, stream>>>(scale, sidx, didx, pred, targ, B, partial, nblk);
    ori_loss_final<<<1, 256, 0, stream>>>(partial, nblk, B, out);
}

// Round 2
// 525.462 us; speedup vs baseline: 1.0115x; 1.0115x over previous
//
#include <hip/hip_runtime.h>

#define DEV __device__ __forceinline__

struct F3 { float x, y, z; };

DEV F3 mk3(float a, float b, float c) { F3 r; r.x = a; r.y = b; r.z = c; return r; }
DEV F3 sub3(F3 a, F3 b) { F3 r; r.x = a.x-b.x; r.y = a.y-b.y; r.z = a.z-b.z; return r; }
DEV F3 cross3(F3 a, F3 b) {
    F3 r;
    r.x = a.y*b.z - a.z*b.y;
    r.y = a.z*b.x - a.x*b.z;
    r.z = a.x*b.y - a.y*b.x;
    return r;
}
DEV float cosv(F3 a, F3 b) {
    float num = a.x*b.x + a.y*b.y + a.z*b.z;
    float na  = a.x*a.x + a.y*a.y + a.z*a.z;
    float nb  = b.x*b.x + b.y*b.y + b.z*b.z;
    return num * rsqrtf(na * nb);
}

__global__ __launch_bounds__(256) void ori_loss_main(
    const float* __restrict__ scale,
    const int*   __restrict__ sidx,
    const int*   __restrict__ didx,
    const float* __restrict__ pred,
    const float* __restrict__ targ,
    int B, float* __restrict__ partial, int nblk)
{
    int b = blockIdx.x * 256 + threadIdx.x;
    float sumj = 0.0f, sumc = 0.0f;
    if (b < B) {
        const float s = scale[0];
        const float* pr = pred + (size_t)b * 72;
        const float* tr = targ + (size_t)b * 78;

        // ---- register-stage full rows with contiguous vector loads ----
        // pred row: 288 B, 16B-aligned -> 18 x float4
        float p[72];
        {
            const float4* pr4 = (const float4*)pr;
            #pragma unroll
            for (int i = 0; i < 18; ++i) {
                float4 v = pr4[i];
                p[4*i+0] = v.x; p[4*i+1] = v.y; p[4*i+2] = v.z; p[4*i+3] = v.w;
            }
        }
        // targ row: 312 B, only 8B-aligned -> 39 x float2
        float t[78];
        {
            const float2* tr2 = (const float2*)tr;
            #pragma unroll
            for (int i = 0; i < 39; ++i) {
                float2 v = tr2[i];
                t[2*i+0] = v.x; t[2*i+1] = v.y;
            }
        }

        // ---- smooth-L1 over 14 gathered joint pairs ----
        // runtime (wave-uniform) indices can't index registers; read global —
        // these lines were just fetched by the staging burst -> L1/L2 hits.
        #pragma unroll
        for (int k = 0; k < 14; ++k) {
            int sj = sidx[k] * 3;
            int dj = didx[k] * 3;
            #pragma unroll
            for (int c = 0; c < 3; ++c) {
                float d  = s * pr[sj + c] - tr[dj + c];
                float ad = fabsf(d);
                sumj += (ad < 1.0f) ? 0.5f * d * d : (ad - 0.5f);
            }
        }

        // ---- fixed-index terms, all from registers ----
        #define P3(j) mk3(p[(j)*3], p[(j)*3+1], p[(j)*3+2])
        #define T3(j) mk3(t[(j)*3], t[(j)*3+1], t[(j)*3+2])

        // pelvis orientation: cross(p2-p0, p1-p0) vs cross(t22-t1, t18-t1)
        sumc += cosv(cross3(sub3(P3(2), P3(0)), sub3(P3(1), P3(0))),
                     cross3(sub3(T3(22), T3(1)), sub3(T3(18), T3(1))));
        // chest orientation: cross(p13-p9, p14-p9) vs cross(t3-t2, t11-t2)
        sumc += cosv(cross3(sub3(P3(13), P3(9)), sub3(P3(14), P3(9))),
                     cross3(sub3(T3(3), T3(2)), sub3(T3(11), T3(2))));

        // 13 bone-direction cosine terms
        #define DIR(pa, pb, ta, tb)                                            \
            sumc += cosv(sub3(P3(pa), P3(pb)), sub3(T3(ta), T3(tb)));
        DIR(2, 1, 22, 18)
        DIR(14, 13, 11, 4)
        DIR(6, 3, 2, 1)
        DIR(5, 2, 23, 22)
        DIR(4, 1, 19, 18)
        DIR(8, 5, 24, 23)
        DIR(7, 4, 20, 19)
        DIR(11, 8, 25, 24)
        DIR(10, 7, 21, 20)
        DIR(19, 17, 13, 12)
        DIR(18, 16, 6, 5)
        DIR(21, 19, 14, 13)
        DIR(20, 18, 7, 6)
        #undef DIR
        #undef P3
        #undef T3
    }

    // 64-lane wave reduction
    #pragma unroll
    for (int off = 32; off; off >>= 1) {
        sumj += __shfl_down(sumj, off);
        sumc += __shfl_down(sumc, off);
    }
    __shared__ float sj[4], sc[4];
    int wid  = threadIdx.x >> 6;
    int lane = threadIdx.x & 63;
    if (lane == 0) { sj[wid] = sumj; sc[wid] = sumc; }
    __syncthreads();
    if (threadIdx.x == 0) {
        partial[blockIdx.x]        = sj[0] + sj[1] + sj[2] + sj[3];
        partial[nblk + blockIdx.x] = sc[0] + sc[1] + sc[2] + sc[3];
    }
}

__global__ __launch_bounds__(256) void ori_loss_final(
    const float* __restrict__ partial, int nblk, int B, float* __restrict__ out)
{
    double dj = 0.0, dc = 0.0;
    for (int i = threadIdx.x; i < nblk; i += 256) {
        dj += (double)partial[i];
        dc += (double)partial[nblk + i];
    }
    #pragma unroll
    for (int off = 32; off; off >>= 1) {
        dj += __shfl_down(dj, off);
        dc += __shfl_down(dc, off);
    }
    __shared__ double wj[4], wc[4];
    int wid  = threadIdx.x >> 6;
    int lane = threadIdx.x & 63;
    if (lane == 0) { wj[wid] = dj; wc[wid] = dc; }
    __syncthreads();
    if (threadIdx.x == 0) {
        double J = wj[0] + wj[1] + wj[2] + wj[3];
        double C = wc[0] + wc[1] + wc[2] + wc[3];
        double jtr  = J / ((double)B * 42.0);
        double loss = jtr + 15.0 - C / (double)B;
        out[0] = (float)loss;
        out[1] = (float)jtr;
    }
}

extern "C" void kernel_launch(void* const* d_in, const int* in_sizes, int n_in,
                              void* d_out, int out_size, void* d_ws, size_t ws_size,
                              hipStream_t stream) {
    const float* scale = (const float*)d_in[0];
    const int*   sidx  = (const int*)d_in[1];
    const int*   didx  = (const int*)d_in[2];
    const float* pred  = (const float*)d_in[3];
    const float* targ  = (const float*)d_in[4];

    int B    = in_sizes[3] / 72;   // pred_jtr is [B, 24, 3]
    int nblk = (B + 255) / 256;

    float* partial = (float*)d_ws;
    float* out     = (float*)d_out;

    ori_loss_main<<<nblk, 256, 0, stream>>>(scale, sidx, didx, pred, targ, B, partial, nblk);
    ori_loss_final<<<1, 256, 0, stream>>>(partial, nblk, B, out);
}

// Round 3
// 146.450 us; speedup vs baseline: 3.6294x; 3.5880x over previous
//
#include <hip/hip_runtime.h>

#define DEV __device__ __forceinline__

struct F3 { float x, y, z; };
DEV F3 mk3(float a, float b, float c) { F3 r; r.x = a; r.y = b; r.z = c; return r; }
DEV F3 sub3(F3 a, F3 b) { return mk3(a.x - b.x, a.y - b.y, a.z - b.z); }
DEV F3 cross3(F3 a, F3 b) {
    return mk3(a.y*b.z - a.z*b.y, a.z*b.x - a.x*b.z, a.x*b.y - a.y*b.x);
}
DEV float cosv(F3 a, F3 b) {
    float num = a.x*b.x + a.y*b.y + a.z*b.z;
    float na  = a.x*a.x + a.y*a.y + a.z*a.z;
    float nb  = b.x*b.x + b.y*b.y + b.z*b.z;
    return num * rsqrtf(na * nb);
}

constexpr int ROWS = 128;   // rows per block
constexpr int TPB  = 128;   // threads per block (2 waves)
constexpr int PSTR = 73;    // padded pred row stride in dwords (odd -> gcd(73%32,32)=1 -> conflict-free)
constexpr int TSTR = 79;    // padded targ row stride in dwords (odd)
constexpr int LDS_BYTES = ROWS * (PSTR + TSTR) * 4;  // 77,824 B -> 2 blocks/CU

__global__ __launch_bounds__(TPB, 1) void ori_loss_main(
    const float* __restrict__ scale,
    const int*   __restrict__ sidx,
    const int*   __restrict__ didx,
    const float* __restrict__ pred,
    const float* __restrict__ targ,
    int B, float* __restrict__ partial, int nblk)
{
    extern __shared__ float lds[];
    float* lp = lds;               // [ROWS][PSTR], data in dwords 0..71 of each row
    float* lt = lds + ROWS * PSTR; // [ROWS][TSTR], data in dwords 0..77 of each row
    __shared__ float redj[2], redc[2];

    const int c0   = blockIdx.x * ROWS;
    const int rows = min(ROWS, B - c0);
    const int tid  = threadIdx.x;

    // ---- coalesced stage: global -> regs (all loads in flight) -> LDS ----
    if (rows == ROWS) {
        const float4* gp = (const float4*)pred + (size_t)c0 * 18;  // 18 f4 per row
        const float2* gt = (const float2*)targ + (size_t)c0 * 39;  // 39 f2 per row
        float4 bp[18];
        float2 bt[39];
        #pragma unroll
        for (int k = 0; k < 18; ++k) bp[k] = gp[tid + TPB * k];
        #pragma unroll
        for (int k = 0; k < 39; ++k) bt[k] = gt[tid + TPB * k];
        #pragma unroll
        for (int k = 0; k < 18; ++k) {
            int i = tid + TPB * k;
            int r = i / 18, j = i - r * 18;
            float* d = lp + r * PSTR + j * 4;
            d[0] = bp[k].x; d[1] = bp[k].y; d[2] = bp[k].z; d[3] = bp[k].w;
        }
        #pragma unroll
        for (int k = 0; k < 39; ++k) {
            int i = tid + TPB * k;
            int r = i / 39, j = i - r * 39;
            float* d = lt + r * TSTR + j * 2;
            d[0] = bt[k].x; d[1] = bt[k].y;
        }
    } else {
        const float4* gp = (const float4*)pred + (size_t)c0 * 18;
        const float2* gt = (const float2*)targ + (size_t)c0 * 39;
        for (int i = tid; i < rows * 18; i += TPB) {
            float4 v = gp[i];
            int r = i / 18, j = i - r * 18;
            float* d = lp + r * PSTR + j * 4;
            d[0] = v.x; d[1] = v.y; d[2] = v.z; d[3] = v.w;
        }
        for (int i = tid; i < rows * 39; i += TPB) {
            float2 v = gt[i];
            int r = i / 39, j = i - r * 39;
            float* d = lt + r * TSTR + j * 2;
            d[0] = v.x; d[1] = v.y;
        }
    }
    __syncthreads();

    // ---- compute: each thread owns one row, reads LDS only ----
    float sumj = 0.0f, sumc = 0.0f;
    if (tid < rows) {
        const float s = scale[0];
        const float* pr = lp + tid * PSTR;
        const float* tr = lt + tid * TSTR;

        // smooth-L1 over 14 runtime-gathered joint pairs (LDS is runtime-indexable)
        #pragma unroll
        for (int k = 0; k < 14; ++k) {
            int sj = sidx[k] * 3;
            int dj = didx[k] * 3;
            #pragma unroll
            for (int c = 0; c < 3; ++c) {
                float d  = s * pr[sj + c] - tr[dj + c];
                float ad = fabsf(d);
                sumj += (ad < 1.0f) ? 0.5f * d * d : (ad - 0.5f);
            }
        }

        #define P3(j) mk3(pr[(j)*3], pr[(j)*3+1], pr[(j)*3+2])
        #define T3(j) mk3(tr[(j)*3], tr[(j)*3+1], tr[(j)*3+2])

        // pelvis orientation
        sumc += cosv(cross3(sub3(P3(2), P3(0)), sub3(P3(1), P3(0))),
                     cross3(sub3(T3(22), T3(1)), sub3(T3(18), T3(1))));
        // chest orientation
        sumc += cosv(cross3(sub3(P3(13), P3(9)), sub3(P3(14), P3(9))),
                     cross3(sub3(T3(3), T3(2)), sub3(T3(11), T3(2))));

        // 13 bone-direction cosine terms
        #define DIR(pa, pb, ta, tb) sumc += cosv(sub3(P3(pa), P3(pb)), sub3(T3(ta), T3(tb)));
        DIR(2, 1, 22, 18)
        DIR(14, 13, 11, 4)
        DIR(6, 3, 2, 1)
        DIR(5, 2, 23, 22)
        DIR(4, 1, 19, 18)
        DIR(8, 5, 24, 23)
        DIR(7, 4, 20, 19)
        DIR(11, 8, 25, 24)
        DIR(10, 7, 21, 20)
        DIR(19, 17, 13, 12)
        DIR(18, 16, 6, 5)
        DIR(21, 19, 14, 13)
        DIR(20, 18, 7, 6)
        #undef DIR
        #undef P3
        #undef T3
    }

    // ---- reduction: 64-lane shuffle, then 2 waves -> block ----
    #pragma unroll
    for (int off = 32; off; off >>= 1) {
        sumj += __shfl_down(sumj, off);
        sumc += __shfl_down(sumc, off);
    }
    int wid  = tid >> 6;
    int lane = tid & 63;
    if (lane == 0) { redj[wid] = sumj; redc[wid] = sumc; }
    __syncthreads();
    if (tid == 0) {
        partial[blockIdx.x]        = redj[0] + redj[1];
        partial[nblk + blockIdx.x] = redc[0] + redc[1];
    }
}

__global__ __launch_bounds__(256) void ori_loss_final(
    const float* __restrict__ partial, int nblk, int B, float* __restrict__ out)
{
    double dj = 0.0, dc = 0.0;
    for (int i = threadIdx.x; i < nblk; i += 256) {
        dj += (double)partial[i];
        dc += (double)partial[nblk + i];
    }
    #pragma unroll
    for (int off = 32; off; off >>= 1) {
        dj += __shfl_down(dj, off);
        dc += __shfl_down(dc, off);
    }
    __shared__ double wj[4], wc[4];
    int wid  = threadIdx.x >> 6;
    int lane = threadIdx.x & 63;
    if (lane == 0) { wj[wid] = dj; wc[wid] = dc; }
    __syncthreads();
    if (threadIdx.x == 0) {
        double J = wj[0] + wj[1] + wj[2] + wj[3];
        double C = wc[0] + wc[1] + wc[2] + wc[3];
        double jtr  = J / ((double)B * 42.0);
        double loss = jtr + 15.0 - C / (double)B;
        out[0] = (float)loss;
        out[1] = (float)jtr;
    }
}

extern "C" void kernel_launch(void* const* d_in, const int* in_sizes, int n_in,
                              void* d_out, int out_size, void* d_ws, size_t ws_size,
                              hipStream_t stream) {
    const float* scale = (const float*)d_in[0];
    const int*   sidx  = (const int*)d_in[1];
    const int*   didx  = (const int*)d_in[2];
    const float* pred  = (const float*)d_in[3];
    const float* targ  = (const float*)d_in[4];

    int B    = in_sizes[3] / 72;          // pred_jtr is [B, 24, 3]
    int nblk = (B + ROWS - 1) / ROWS;

    float* partial = (float*)d_ws;
    float* out     = (float*)d_out;

    ori_loss_main<<<nblk, TPB, LDS_BYTES, stream>>>(scale, sidx, didx, pred, targ,
                                                    B, partial, nblk);
    ori_loss_final<<<1, 256, 0, stream>>>(partial, nblk, B, out);
}

// Round 4
// 123.722 us; speedup vs baseline: 4.2961x; 1.1837x over previous
//
#include <hip/hip_runtime.h>

#define DEV __device__ __forceinline__

struct F3 { float x, y, z; };
DEV F3 mk3(float a, float b, float c) { F3 r; r.x = a; r.y = b; r.z = c; return r; }
DEV F3 sub3(F3 a, F3 b) { return mk3(a.x - b.x, a.y - b.y, a.z - b.z); }
DEV F3 cross3(F3 a, F3 b) {
    return mk3(a.y*b.z - a.z*b.y, a.z*b.x - a.x*b.z, a.x*b.y - a.y*b.x);
}
DEV float cosv(F3 a, F3 b) {
    float num = a.x*b.x + a.y*b.y + a.z*b.z;
    float na  = a.x*a.x + a.y*a.y + a.z*a.z;
    float nb  = b.x*b.x + b.y*b.y + b.z*b.z;
    return num * rsqrtf(na * nb);
}

constexpr int ROWS = 128;   // rows per tile
constexpr int TPB  = 128;   // threads per block (2 waves)
constexpr int PSTR = 73;    // padded pred row stride (odd -> conflict-free lane stride)
constexpr int TSTR = 79;    // padded targ row stride (odd)
constexpr int LDS_BYTES = ROWS * (PSTR + TSTR) * 4;  // 77,824 B -> 2 blocks/CU
constexpr int NBMAX = 512;  // 2 blocks/CU * 256 CUs

__global__ __launch_bounds__(TPB, 1) void ori_loss_main(
    const float* __restrict__ scale,
    const int*   __restrict__ sidx,
    const int*   __restrict__ didx,
    const float* __restrict__ pred,
    const float* __restrict__ targ,
    int B, int ntiles, int nb,
    float* __restrict__ partial)
{
    extern __shared__ float lds[];
    float* lp = lds;               // [ROWS][PSTR]
    float* lt = lds + ROWS * PSTR; // [ROWS][TSTR]
    __shared__ float redj[2], redc[2];

    const int tid = threadIdx.x;
    const float s = scale[0];

    // wave-uniform gather indices -> SGPRs
    int sj[14], dj[14];
    #pragma unroll
    for (int k = 0; k < 14; ++k) { sj[k] = sidx[k] * 3; dj[k] = didx[k] * 3; }

    const float4* gp = (const float4*)pred;   // B*18 float4
    const float2* gt = (const float2*)targ;   // B*39 float2
    const long maxp = (long)B * 18 - 1;
    const long maxt = (long)B * 39 - 1;

    float4 bp[18];
    float2 bt[39];

    auto load_tile = [&](int t) {
        long basep = (long)t * (ROWS * 18);
        long baset = (long)t * (ROWS * 39);
        #pragma unroll
        for (int k = 0; k < 18; ++k) {
            long i = basep + tid + TPB * k;
            bp[k] = gp[i > maxp ? maxp : i];
        }
        #pragma unroll
        for (int k = 0; k < 39; ++k) {
            long i = baset + tid + TPB * k;
            bt[k] = gt[i > maxt ? maxt : i];
        }
    };

    float sumj = 0.0f, sumc = 0.0f;
    int t = blockIdx.x;
    load_tile(t);                         // prologue: tile t in flight

    for (;;) {
        __syncthreads();                  // prior compute done reading LDS
        // regs -> LDS (compiler inserts the vmcnt waits here, at first use)
        #pragma unroll
        for (int k = 0; k < 18; ++k) {
            int i = tid + TPB * k;
            int r = i / 18, j = i - r * 18;
            float* d = lp + r * PSTR + j * 4;
            d[0] = bp[k].x; d[1] = bp[k].y; d[2] = bp[k].z; d[3] = bp[k].w;
        }
        #pragma unroll
        for (int k = 0; k < 39; ++k) {
            int i = tid + TPB * k;
            int r = i / 39, j = i - r * 39;
            float* d = lt + r * TSTR + j * 2;
            d[0] = bt[k].x; d[1] = bt[k].y;
        }
        __syncthreads();

        int tn = t + nb;
        if (tn < ntiles) load_tile(tn);   // issue next tile's loads NOW
        asm volatile("" ::: "memory");    // pin loads above compute (anti-sink)

        // ---- compute tile t from LDS ----
        int rows = min(ROWS, B - t * ROWS);
        if (tid < rows) {
            const float* pr = lp + tid * PSTR;
            const float* tr = lt + tid * TSTR;

            #pragma unroll
            for (int k = 0; k < 14; ++k) {
                #pragma unroll
                for (int c = 0; c < 3; ++c) {
                    float d  = s * pr[sj[k] + c] - tr[dj[k] + c];
                    float ad = fabsf(d);
                    sumj += (ad < 1.0f) ? 0.5f * d * d : (ad - 0.5f);
                }
            }

            #define P3(j) mk3(pr[(j)*3], pr[(j)*3+1], pr[(j)*3+2])
            #define T3(j) mk3(tr[(j)*3], tr[(j)*3+1], tr[(j)*3+2])
            sumc += cosv(cross3(sub3(P3(2), P3(0)), sub3(P3(1), P3(0))),
                         cross3(sub3(T3(22), T3(1)), sub3(T3(18), T3(1))));
            sumc += cosv(cross3(sub3(P3(13), P3(9)), sub3(P3(14), P3(9))),
                         cross3(sub3(T3(3), T3(2)), sub3(T3(11), T3(2))));
            #define DIR(pa, pb, ta, tb) sumc += cosv(sub3(P3(pa), P3(pb)), sub3(T3(ta), T3(tb)));
            DIR(2, 1, 22, 18)
            DIR(14, 13, 11, 4)
            DIR(6, 3, 2, 1)
            DIR(5, 2, 23, 22)
            DIR(4, 1, 19, 18)
            DIR(8, 5, 24, 23)
            DIR(7, 4, 20, 19)
            DIR(11, 8, 25, 24)
            DIR(10, 7, 21, 20)
            DIR(19, 17, 13, 12)
            DIR(18, 16, 6, 5)
            DIR(21, 19, 14, 13)
            DIR(20, 18, 7, 6)
            #undef DIR
            #undef P3
            #undef T3
        }

        if (tn >= ntiles) break;
        t = tn;
    }

    // ---- block reduction ----
    #pragma unroll
    for (int off = 32; off; off >>= 1) {
        sumj += __shfl_down(sumj, off);
        sumc += __shfl_down(sumc, off);
    }
    int wid  = tid >> 6;
    int lane = tid & 63;
    if (lane == 0) { redj[wid] = sumj; redc[wid] = sumc; }
    __syncthreads();
    if (tid == 0) {
        partial[blockIdx.x]      = redj[0] + redj[1];
        partial[nb + blockIdx.x] = redc[0] + redc[1];
    }
}

__global__ __launch_bounds__(256) void ori_loss_final(
    const float* __restrict__ partial, int nblk, int B, float* __restrict__ out)
{
    double dj = 0.0, dc = 0.0;
    for (int i = threadIdx.x; i < nblk; i += 256) {
        dj += (double)partial[i];
        dc += (double)partial[nblk + i];
    }
    #pragma unroll
    for (int off = 32; off; off >>= 1) {
        dj += __shfl_down(dj, off);
        dc += __shfl_down(dc, off);
    }
    __shared__ double wj[4], wc[4];
    int wid  = threadIdx.x >> 6;
    int lane = threadIdx.x & 63;
    if (lane == 0) { wj[wid] = dj; wc[wid] = dc; }
    __syncthreads();
    if (threadIdx.x == 0) {
        double J = wj[0] + wj[1] + wj[2] + wj[3];
        double C = wc[0] + wc[1] + wc[2] + wc[3];
        double jtr  = J / ((double)B * 42.0);
        double loss = jtr + 15.0 - C / (double)B;
        out[0] = (float)loss;
        out[1] = (float)jtr;
    }
}

extern "C" void kernel_launch(void* const* d_in, const int* in_sizes, int n_in,
                              void* d_out, int out_size, void* d_ws, size_t ws_size,
                              hipStream_t stream) {
    const float* scale = (const float*)d_in[0];
    const int*   sidx  = (const int*)d_in[1];
    const int*   didx  = (const int*)d_in[2];
    const float* pred  = (const float*)d_in[3];
    const float* targ  = (const float*)d_in[4];

    int B      = in_sizes[3] / 72;               // pred_jtr is [B, 24, 3]
    int ntiles = (B + ROWS - 1) / ROWS;
    int nb     = ntiles < NBMAX ? ntiles : NBMAX;

    float* partial = (float*)d_ws;
    float* out     = (float*)d_out;

    ori_loss_main<<<nb, TPB, LDS_BYTES, stream>>>(scale, sidx, didx, pred, targ,
                                                  B, ntiles, nb, partial);
    ori_loss_final<<<1, 256, 0, stream>>>(partial, nb, B, out);
}

// Round 5
// 117.587 us; speedup vs baseline: 4.5203x; 1.0522x over previous
//
#include <hip/hip_runtime.h>

#define DEV __device__ __forceinline__

struct F3 { float x, y, z; };
DEV F3 mk3(float a, float b, float c) { F3 r; r.x = a; r.y = b; r.z = c; return r; }
DEV F3 sub3(F3 a, F3 b) { return mk3(a.x - b.x, a.y - b.y, a.z - b.z); }
DEV F3 cross3(F3 a, F3 b) {
    return mk3(a.y*b.z - a.z*b.y, a.z*b.x - a.x*b.z, a.x*b.y - a.y*b.x);
}
DEV float cosv(F3 a, F3 b) {
    float num = a.x*b.x + a.y*b.y + a.z*b.z;
    float na  = a.x*a.x + a.y*a.y + a.z*a.z;
    float nb  = b.x*b.x + b.y*b.y + b.z*b.z;
    return num * rsqrtf(na * nb);
}

constexpr int ROWS = 64;    // rows per tile
constexpr int TPB  = 64;    // one wave per block -> near-free syncs, 4 independent pipelines/CU
constexpr int PSTR = 73;    // padded pred row stride (odd -> conflict-free compute reads)
constexpr int TSTR = 79;    // padded targ row stride (odd)
constexpr int LDS_BYTES = ROWS * (PSTR + TSTR) * 4;  // 38,912 B -> 4 blocks/CU
constexpr int NBMAX = 1024; // 4 blocks/CU * 256 CUs (multiple of 256 -> uniform CU load)

__global__ __launch_bounds__(TPB, 1) void ori_loss_main(
    const float* __restrict__ scale,
    const int*   __restrict__ sidx,
    const int*   __restrict__ didx,
    const float* __restrict__ pred,
    const float* __restrict__ targ,
    int B, int ntiles, int nb,
    float* __restrict__ partial)
{
    extern __shared__ float lds[];
    float* lp = lds;               // [ROWS][PSTR]
    float* lt = lds + ROWS * PSTR; // [ROWS][TSTR]

    const int tid = threadIdx.x;
    const float s = scale[0];

    // wave-uniform gather indices -> SGPRs
    int sj[14], dj[14];
    #pragma unroll
    for (int k = 0; k < 14; ++k) { sj[k] = sidx[k] * 3; dj[k] = didx[k] * 3; }

    const float4* gp = (const float4*)pred;   // B*18 float4
    const float2* gt = (const float2*)targ;   // B*39 float2
    const long maxp = (long)B * 18 - 1;
    const long maxt = (long)B * 39 - 1;

    float4 bp[18];
    float2 bt[39];

    auto load_tile = [&](int t) {
        long basep = (long)t * (ROWS * 18);
        long baset = (long)t * (ROWS * 39);
        #pragma unroll
        for (int k = 0; k < 18; ++k) {
            long i = basep + tid + TPB * k;
            bp[k] = gp[i > maxp ? maxp : i];
        }
        #pragma unroll
        for (int k = 0; k < 39; ++k) {
            long i = baset + tid + TPB * k;
            bt[k] = gt[i > maxt ? maxt : i];
        }
    };

    float sumj = 0.0f, sumc = 0.0f;
    int t = blockIdx.x;
    load_tile(t);                         // prologue: tile t in flight

    for (;;) {
        __syncthreads();                  // prior compute done reading LDS
        // regs -> LDS (compiler inserts vmcnt waits here, at first use)
        #pragma unroll
        for (int k = 0; k < 18; ++k) {
            int i = tid + TPB * k;
            int r = i / 18, j = i - r * 18;
            float* d = lp + r * PSTR + j * 4;
            d[0] = bp[k].x; d[1] = bp[k].y; d[2] = bp[k].z; d[3] = bp[k].w;
        }
        #pragma unroll
        for (int k = 0; k < 39; ++k) {
            int i = tid + TPB * k;
            int r = i / 39, j = i - r * 39;
            float* d = lt + r * TSTR + j * 2;
            d[0] = bt[k].x; d[1] = bt[k].y;
        }
        __syncthreads();

        int tn = t + nb;
        if (tn < ntiles) load_tile(tn);   // issue next tile's loads NOW
        asm volatile("" ::: "memory");    // pin loads above compute (anti-sink)

        // ---- compute tile t from LDS ----
        int rows = min(ROWS, B - t * ROWS);
        if (tid < rows) {
            const float* pr = lp + tid * PSTR;
            const float* tr = lt + tid * TSTR;

            #pragma unroll
            for (int k = 0; k < 14; ++k) {
                #pragma unroll
                for (int c = 0; c < 3; ++c) {
                    float d  = s * pr[sj[k] + c] - tr[dj[k] + c];
                    float ad = fabsf(d);
                    sumj += (ad < 1.0f) ? 0.5f * d * d : (ad - 0.5f);
                }
            }

            #define P3(j) mk3(pr[(j)*3], pr[(j)*3+1], pr[(j)*3+2])
            #define T3(j) mk3(tr[(j)*3], tr[(j)*3+1], tr[(j)*3+2])
            sumc += cosv(cross3(sub3(P3(2), P3(0)), sub3(P3(1), P3(0))),
                         cross3(sub3(T3(22), T3(1)), sub3(T3(18), T3(1))));
            sumc += cosv(cross3(sub3(P3(13), P3(9)), sub3(P3(14), P3(9))),
                         cross3(sub3(T3(3), T3(2)), sub3(T3(11), T3(2))));
            #define DIR(pa, pb, ta, tb) sumc += cosv(sub3(P3(pa), P3(pb)), sub3(T3(ta), T3(tb)));
            DIR(2, 1, 22, 18)
            DIR(14, 13, 11, 4)
            DIR(6, 3, 2, 1)
            DIR(5, 2, 23, 22)
            DIR(4, 1, 19, 18)
            DIR(8, 5, 24, 23)
            DIR(7, 4, 20, 19)
            DIR(11, 8, 25, 24)
            DIR(10, 7, 21, 20)
            DIR(19, 17, 13, 12)
            DIR(18, 16, 6, 5)
            DIR(21, 19, 14, 13)
            DIR(20, 18, 7, 6)
            #undef DIR
            #undef P3
            #undef T3
        }

        if (tn >= ntiles) break;
        t = tn;
    }

    // ---- single-wave reduction ----
    #pragma unroll
    for (int off = 32; off; off >>= 1) {
        sumj += __shfl_down(sumj, off);
        sumc += __shfl_down(sumc, off);
    }
    if (tid == 0) {
        partial[blockIdx.x]      = sumj;
        partial[nb + blockIdx.x] = sumc;
    }
}

__global__ __launch_bounds__(256) void ori_loss_final(
    const float* __restrict__ partial, int nblk, int B, float* __restrict__ out)
{
    double dj = 0.0, dc = 0.0;
    for (int i = threadIdx.x; i < nblk; i += 256) {
        dj += (double)partial[i];
        dc += (double)partial[nblk + i];
    }
    #pragma unroll
    for (int off = 32; off; off >>= 1) {
        dj += __shfl_down(dj, off);
        dc += __shfl_down(dc, off);
    }
    __shared__ double wj[4], wc[4];
    int wid  = threadIdx.x >> 6;
    int lane = threadIdx.x & 63;
    if (lane == 0) { wj[wid] = dj; wc[wid] = dc; }
    __syncthreads();
    if (threadIdx.x == 0) {
        double J = wj[0] + wj[1] + wj[2] + wj[3];
        double C = wc[0] + wc[1] + wc[2] + wc[3];
        double jtr  = J / ((double)B * 42.0);
        double loss = jtr + 15.0 - C / (double)B;
        out[0] = (float)loss;
        out[1] = (float)jtr;
    }
}

extern "C" void kernel_launch(void* const* d_in, const int* in_sizes, int n_in,
                              void* d_out, int out_size, void* d_ws, size_t ws_size,
                              hipStream_t stream) {
    const float* scale = (const float*)d_in[0];
    const int*   sidx  = (const int*)d_in[1];
    const int*   didx  = (const int*)d_in[2];
    const float* pred  = (const float*)d_in[3];
    const float* targ  = (const float*)d_in[4];

    int B      = in_sizes[3] / 72;               // pred_jtr is [B, 24, 3]
    int ntiles = (B + ROWS - 1) / ROWS;
    int nb     = ntiles < NBMAX ? ntiles : NBMAX;

    float* partial = (float*)d_ws;
    float* out     = (float*)d_out;

    ori_loss_main<<<nb, TPB, LDS_BYTES, stream>>>(scale, sidx, didx, pred, targ,
                                                  B, ntiles, nb, partial);
    ori_loss_final<<<1, 256, 0, stream>>>(partial, nb, B, out);
}

// Round 6
// 114.017 us; speedup vs baseline: 4.6618x; 1.0313x over previous
//
#include <hip/hip_runtime.h>

#define DEV __device__ __forceinline__

struct F3 { float x, y, z; };
DEV F3 mk3(float a, float b, float c) { F3 r; r.x = a; r.y = b; r.z = c; return r; }
DEV F3 sub3(F3 a, F3 b) { return mk3(a.x - b.x, a.y - b.y, a.z - b.z); }
DEV F3 cross3(F3 a, F3 b) {
    return mk3(a.y*b.z - a.z*b.y, a.z*b.x - a.x*b.z, a.x*b.y - a.y*b.x);
}
DEV float cosv(F3 a, F3 b) {
    float num = a.x*b.x + a.y*b.y + a.z*b.z;
    float na  = a.x*a.x + a.y*a.y + a.z*a.z;
    float nb  = b.x*b.x + b.y*b.y + b.z*b.z;
    return num * rsqrtf(na * nb);
}

constexpr int ROWS = 64;    // rows per tile
constexpr int TPB  = 64;    // one wave per block: near-free syncs, 4 independent pipelines/CU
constexpr int PSTR = 73;    // padded pred row stride (odd -> conflict-free compute reads)
constexpr int TSTR = 79;    // padded targ row stride (odd)
constexpr int LDS_BYTES = ROWS * (PSTR + TSTR) * 4;  // 38,912 B -> 4 blocks/CU
constexpr int NBMAX = 1024; // 4 blocks/CU * 256 CUs

__global__ __launch_bounds__(TPB, 1) void ori_loss_main(
    const float* __restrict__ scale,
    const int*   __restrict__ sidx,
    const int*   __restrict__ didx,
    const float* __restrict__ pred,
    const float* __restrict__ targ,
    int B, int ntiles, int nb,
    float* __restrict__ partial)
{
    extern __shared__ float lds[];
    float* lp = lds;               // [ROWS][PSTR]
    float* lt = lds + ROWS * PSTR; // [ROWS][TSTR]

    const int tid = threadIdx.x;
    const float s = scale[0];

    // wave-uniform gather indices -> SGPRs
    int sj[14], dj[14];
    #pragma unroll
    for (int k = 0; k < 14; ++k) { sj[k] = sidx[k] * 3; dj[k] = didx[k] * 3; }

    const float4* gp = (const float4*)pred;   // B*18 float4
    const float2* gt = (const float2*)targ;   // B*39 float2
    const long maxp = (long)B * 18 - 1;
    const long maxt = (long)B * 39 - 1;

    float4 bp[18];
    float2 bt[39];

    auto load_pred = [&](int t) {
        long basep = (long)t * (ROWS * 18);
        #pragma unroll
        for (int k = 0; k < 18; ++k) {
            long i = basep + tid + TPB * k;
            bp[k] = gp[i > maxp ? maxp : i];
        }
    };
    auto load_targ = [&](int t) {
        long baset = (long)t * (ROWS * 39);
        #pragma unroll
        for (int k = 0; k < 39; ++k) {
            long i = baset + tid + TPB * k;
            bt[k] = gt[i > maxt ? maxt : i];
        }
    };

    float sumj = 0.0f, sumc = 0.0f;
    int t = blockIdx.x;
    load_targ(t);                          // prologue: tile t in flight
    load_pred(t);

    for (;;) {
        __syncthreads();                   // prior compute done reading LDS
        int tn = t + nb;
        bool more = tn < ntiles;

        // ---- targ regs -> LDS, then immediately re-issue targ loads(t+1) ----
        #pragma unroll
        for (int k = 0; k < 39; ++k) {
            int i = tid + TPB * k;
            int r = i / 39, j = i - r * 39;
            float* d = lt + r * TSTR + j * 2;
            d[0] = bt[k].x; d[1] = bt[k].y;
        }
        if (more) load_targ(tn);           // in flight while pred writes run
        asm volatile("" ::: "memory");

        // ---- pred regs -> LDS, then re-issue pred loads(t+1) ----
        #pragma unroll
        for (int k = 0; k < 18; ++k) {
            int i = tid + TPB * k;
            int r = i / 18, j = i - r * 18;
            float* d = lp + r * PSTR + j * 4;
            d[0] = bp[k].x; d[1] = bp[k].y; d[2] = bp[k].z; d[3] = bp[k].w;
        }
        if (more) load_pred(tn);
        asm volatile("" ::: "memory");     // pin loads above compute (anti-sink)
        __syncthreads();

        // ---- compute tile t from LDS ----
        int rows = min(ROWS, B - t * ROWS);
        if (tid < rows) {
            const float* pr = lp + tid * PSTR;
            const float* tr = lt + tid * TSTR;

            #pragma unroll
            for (int k = 0; k < 14; ++k) {
                #pragma unroll
                for (int c = 0; c < 3; ++c) {
                    float d  = s * pr[sj[k] + c] - tr[dj[k] + c];
                    float ad = fabsf(d);
                    sumj += (ad < 1.0f) ? 0.5f * d * d : (ad - 0.5f);
                }
            }

            #define P3(j) mk3(pr[(j)*3], pr[(j)*3+1], pr[(j)*3+2])
            #define T3(j) mk3(tr[(j)*3], tr[(j)*3+1], tr[(j)*3+2])
            sumc += cosv(cross3(sub3(P3(2), P3(0)), sub3(P3(1), P3(0))),
                         cross3(sub3(T3(22), T3(1)), sub3(T3(18), T3(1))));
            sumc += cosv(cross3(sub3(P3(13), P3(9)), sub3(P3(14), P3(9))),
                         cross3(sub3(T3(3), T3(2)), sub3(T3(11), T3(2))));
            #define DIR(pa, pb, ta, tb) sumc += cosv(sub3(P3(pa), P3(pb)), sub3(T3(ta), T3(tb)));
            DIR(2, 1, 22, 18)
            DIR(14, 13, 11, 4)
            DIR(6, 3, 2, 1)
            DIR(5, 2, 23, 22)
            DIR(4, 1, 19, 18)
            DIR(8, 5, 24, 23)
            DIR(7, 4, 20, 19)
            DIR(11, 8, 25, 24)
            DIR(10, 7, 21, 20)
            DIR(19, 17, 13, 12)
            DIR(18, 16, 6, 5)
            DIR(21, 19, 14, 13)
            DIR(20, 18, 7, 6)
            #undef DIR
            #undef P3
            #undef T3
        }

        if (!more) break;
        t = tn;
    }

    // ---- single-wave reduction ----
    #pragma unroll
    for (int off = 32; off; off >>= 1) {
        sumj += __shfl_down(sumj, off);
        sumc += __shfl_down(sumc, off);
    }
    if (tid == 0) {
        partial[blockIdx.x]      = sumj;
        partial[nb + blockIdx.x] = sumc;
    }
}

__global__ __launch_bounds__(256) void ori_loss_final(
    const float* __restrict__ partial, int nblk, int B, float* __restrict__ out)
{
    double dj = 0.0, dc = 0.0;
    for (int i = threadIdx.x; i < nblk; i += 256) {
        dj += (double)partial[i];
        dc += (double)partial[nblk + i];
    }
    #pragma unroll
    for (int off = 32; off; off >>= 1) {
        dj += __shfl_down(dj, off);
        dc += __shfl_down(dc, off);
    }
    __shared__ double wj[4], wc[4];
    int wid  = threadIdx.x >> 6;
    int lane = threadIdx.x & 63;
    if (lane == 0) { wj[wid] = dj; wc[wid] = dc; }
    __syncthreads();
    if (threadIdx.x == 0) {
        double J = wj[0] + wj[1] + wj[2] + wj[3];
        double C = wc[0] + wc[1] + wc[2] + wc[3];
        double jtr  = J / ((double)B * 42.0);
        double loss = jtr + 15.0 - C / (double)B;
        out[0] = (float)loss;
        out[1] = (float)jtr;
    }
}

extern "C" void kernel_launch(void* const* d_in, const int* in_sizes, int n_in,
                              void* d_out, int out_size, void* d_ws, size_t ws_size,
                              hipStream_t stream) {
    const float* scale = (const float*)d_in[0];
    const int*   sidx  = (const int*)d_in[1];
    const int*   didx  = (const int*)d_in[2];
    const float* pred  = (const float*)d_in[3];
    const float* targ  = (const float*)d_in[4];

    int B      = in_sizes[3] / 72;               // pred_jtr is [B, 24, 3]
    int ntiles = (B + ROWS - 1) / ROWS;
    int nb     = ntiles < NBMAX ? ntiles : NBMAX;

    float* partial = (float*)d_ws;
    float* out     = (float*)d_out;

    ori_loss_main<<<nb, TPB, LDS_BYTES, stream>>>(scale, sidx, didx, pred, targ,
                                                  B, ntiles, nb, partial);
    ori_loss_final<<<1, 256, 0, stream>>>(partial, nb, B, out);
}